// Round 1
// baseline (14119.969 us; speedup 1.0000x reference)
//
#include <hip/hip_runtime.h>

#define DEV __device__ __forceinline__

typedef float f32x4 __attribute__((ext_vector_type(4)));
typedef __bf16 bf16x8_t __attribute__((ext_vector_type(8)));

#define VSZ 32000
#define EDIM 256
#define HDIM 512
#define BSZ 16
#define TEN 512
#define TDN 128
#define G3H 1536

DEV unsigned short f2bf(float f) {
  unsigned u = __builtin_bit_cast(unsigned, f);
  return (unsigned short)((u + 0x7fffu + ((u >> 16) & 1u)) >> 16);
}
DEV float bf2f(unsigned short s) {
  unsigned u = ((unsigned)s) << 16;
  return __builtin_bit_cast(float, u);
}
DEV __bf16 bfr(float f) {
  unsigned short s = f2bf(f);
  return __builtin_bit_cast(__bf16, s);
}
DEV bf16x8_t cvt8(const float* p) {
  float4 a = *(const float4*)p;
  float4 b = *(const float4*)(p + 4);
  bf16x8_t r;
  r[0] = bfr(a.x); r[1] = bfr(a.y); r[2] = bfr(a.z); r[3] = bfr(a.w);
  r[4] = bfr(b.x); r[5] = bfr(b.y); r[6] = bfr(b.z); r[7] = bfr(b.w);
  return r;
}
DEV float sigm(float x) { return 1.0f / (1.0f + __expf(-x)); }
DEV float tanh1(float x) { float e = __expf(2.0f * x); return 1.0f - 2.0f / (e + 1.0f); }

#define MFMA16(a, b, c) __builtin_amdgcn_mfma_f32_16x16x32_bf16((a), (b), (c), 0, 0, 0)

// device-scope grid barrier (counter+generation). All blocks co-resident by construction.
DEV void gbar(unsigned* bars, unsigned nb) {
  __threadfence();
  __syncthreads();
  if (threadIdx.x == 0) {
    unsigned g = __hip_atomic_load(bars + 1, __ATOMIC_RELAXED, __HIP_MEMORY_SCOPE_AGENT);
    unsigned old = __hip_atomic_fetch_add(bars, 1u, __ATOMIC_ACQ_REL, __HIP_MEMORY_SCOPE_AGENT);
    if (old == nb - 1u) {
      __hip_atomic_store(bars, 0u, __ATOMIC_RELAXED, __HIP_MEMORY_SCOPE_AGENT);
      __hip_atomic_fetch_add(bars + 1, 1u, __ATOMIC_RELEASE, __HIP_MEMORY_SCOPE_AGENT);
    } else {
      while (__hip_atomic_load(bars + 1, __ATOMIC_ACQUIRE, __HIP_MEMORY_SCOPE_AGENT) == g)
        __builtin_amdgcn_s_sleep(2);
    }
  }
  __syncthreads();
  __threadfence();
}

__global__ void zerok(unsigned* p, int n) {
  int i = blockIdx.x * blockDim.x + threadIdx.x;
  if (i < n) p[i] = 0u;
}

// fp32 -> bf16, same layout
__global__ __launch_bounds__(256) void castP(const float* __restrict__ in,
                                             unsigned short* __restrict__ out, int n4) {
  int i = blockIdx.x * blockDim.x + threadIdx.x;
  int stride = gridDim.x * blockDim.x;
  for (; i < n4; i += stride) {
    float4 v = ((const float4*)in)[i];
    ushort4 o;
    o.x = f2bf(v.x); o.y = f2bf(v.y); o.z = f2bf(v.z); o.w = f2bf(v.w);
    ((ushort4*)out)[i] = o;
  }
}

// fp32 [K][N] -> bf16 [N][K] (transpose)
__global__ __launch_bounds__(256) void castT(const float* __restrict__ in,
                                             unsigned short* __restrict__ out, int K, int N) {
  __shared__ unsigned short tile[32][33];
  int tx = threadIdx.x & 31, ty = threadIdx.x >> 5;
  int bx = blockIdx.x, by = blockIdx.y;
  for (int i = ty; i < 32; i += 8)
    tile[i][tx] = f2bf(in[(size_t)(by * 32 + i) * N + bx * 32 + tx]);
  __syncthreads();
  for (int i = ty; i < 32; i += 8)
    out[(size_t)(bx * 32 + i) * K + by * 32 + tx] = tile[tx][i];
}

// C[M][N] (f32 or bf16) = A[M][K]bf16 (optionally gathered rows) @ BT[N][K]bf16 + bias[N]
// M%128==0, N%128==0, K%64==0
template <bool GATHER, bool OUTBF>
__global__ __launch_bounds__(256) void gemm_bf16(
    const unsigned short* __restrict__ A, const int* __restrict__ tok,
    const unsigned short* __restrict__ BT, const float* __restrict__ bias,
    void* __restrict__ Cout, int M, int N, int K, int lda, int ldb) {
  __shared__ unsigned short As[128][72];
  __shared__ unsigned short Bs[128][72];
  const int tid = threadIdx.x;
  const int lane = tid & 63, w = tid >> 6;
  const int wr = w >> 1, wc = w & 1;
  const int m0 = blockIdx.y * 128, n0 = blockIdx.x * 128;

  const f32x4 zz = {0.f, 0.f, 0.f, 0.f};
  f32x4 acc[4][4];
#pragma unroll
  for (int i = 0; i < 4; ++i)
#pragma unroll
    for (int j = 0; j < 4; ++j) acc[i][j] = zz;

  for (int kt = 0; kt < K; kt += 64) {
#pragma unroll
    for (int it = 0; it < 4; ++it) {
      int c = it * 256 + tid;
      int row = c >> 3, kb = c & 7;
      size_t arow = GATHER ? (size_t)tok[m0 + row] : (size_t)(m0 + row);
      *(uint4*)&As[row][kb * 8] = *(const uint4*)(A + arow * lda + kt + kb * 8);
      *(uint4*)&Bs[row][kb * 8] = *(const uint4*)(BT + (size_t)(n0 + row) * ldb + kt + kb * 8);
    }
    __syncthreads();
#pragma unroll
    for (int ks = 0; ks < 2; ++ks) {
      int kk = ks * 32 + ((lane >> 4) << 3);
      bf16x8_t af[4], bg[4];
#pragma unroll
      for (int fm = 0; fm < 4; ++fm)
        af[fm] = *(const bf16x8_t*)&As[wr * 64 + fm * 16 + (lane & 15)][kk];
#pragma unroll
      for (int fn = 0; fn < 4; ++fn)
        bg[fn] = *(const bf16x8_t*)&Bs[wc * 64 + fn * 16 + (lane & 15)][kk];
#pragma unroll
      for (int fm = 0; fm < 4; ++fm)
#pragma unroll
        for (int fn = 0; fn < 4; ++fn)
          acc[fm][fn] = MFMA16(af[fm], bg[fn], acc[fm][fn]);
    }
    __syncthreads();
  }
#pragma unroll
  for (int fn = 0; fn < 4; ++fn) {
    int n = n0 + wc * 64 + fn * 16 + (lane & 15);
    float bv = bias[n];
#pragma unroll
    for (int fm = 0; fm < 4; ++fm) {
      int mb = m0 + wr * 64 + fm * 16 + ((lane >> 4) << 2);
#pragma unroll
      for (int j = 0; j < 4; ++j) {
        float v = acc[fm][fn][j] + bv;
        if (OUTBF)
          ((unsigned short*)Cout)[(size_t)(mb + j) * N + n] = f2bf(v);
        else
          ((float*)Cout)[(size_t)(mb + j) * N + n] = v;
      }
    }
  }
}

// Persistent encoder GRU. grid=32 blocks, block jf owns h columns [jf*16, jf*16+16).
// gh = h@rk + br via MFMA (h fp32 state, converted to bf16 per step), x-part precomputed in gxe.
__global__ __launch_bounds__(256) void encoder_gru(
    const float* __restrict__ gxe,            // [B*TE][3H] = x@k + bi
    const unsigned short* __restrict__ rkT,   // [3H][H] bf16
    const int* __restrict__ etok,             // [B][TE]
    const float* __restrict__ ebr,            // [3H]
    float* __restrict__ hbuf,                 // [2][B][H]
    unsigned short* __restrict__ eob,         // enc_out bf16 [B*TE][H]
    unsigned* __restrict__ bars) {
  __shared__ unsigned short wlds[48][520];    // 3 gates x 16 j rows, 512 k (pitch 520: 2-way banks)
  __shared__ float partials[4][3][16][16];
  const int tid = threadIdx.x, lane = tid & 63, w = tid >> 6;
  const int jf = blockIdx.x;
  const f32x4 zz = {0.f, 0.f, 0.f, 0.f};

  for (int idx = tid; idx < 3072; idx += 256) {  // 48*512/8 chunks
    int r = idx >> 6, kb = idx & 63;
    int g = r >> 4, jj = r & 15;
    *(uint4*)&wlds[r][kb * 8] = *(const uint4*)(rkT + (size_t)(g * 512 + jf * 16 + jj) * 512 + kb * 8);
  }
  { // h0 = 0
    int b = tid >> 4, j = tid & 15;
    hbuf[b * 512 + jf * 16 + j] = 0.0f;
  }
  gbar(bars, 32);

  for (int t = 0; t < 512; ++t) {
    const float* hcur = hbuf + (t & 1) * 8192;
    float* hnxt = hbuf + ((t & 1) ^ 1) * 8192;
    f32x4 acc[3];
    acc[0] = zz; acc[1] = zz; acc[2] = zz;
#pragma unroll
    for (int ks = 0; ks < 4; ++ks) {           // wave w covers k in [w*128, w*128+128)
      int kk = w * 128 + ks * 32 + ((lane >> 4) << 3);
      bf16x8_t af = cvt8(hcur + (lane & 15) * 512 + kk);
#pragma unroll
      for (int g = 0; g < 3; ++g) {
        bf16x8_t bg = *(const bf16x8_t*)&wlds[g * 16 + (lane & 15)][kk];
        acc[g] = MFMA16(af, bg, acc[g]);
      }
    }
#pragma unroll
    for (int g = 0; g < 3; ++g)
#pragma unroll
      for (int r4 = 0; r4 < 4; ++r4)
        partials[w][g][(lane >> 4) * 4 + r4][lane & 15] = acc[g][r4];
    __syncthreads();
    {
      int b = tid >> 4, j = tid & 15, jg = jf * 16 + j;
      float g0 = partials[0][0][b][j] + partials[1][0][b][j] + partials[2][0][b][j] + partials[3][0][b][j] + ebr[jg];
      float g1 = partials[0][1][b][j] + partials[1][1][b][j] + partials[2][1][b][j] + partials[3][1][b][j] + ebr[512 + jg];
      float g2 = partials[0][2][b][j] + partials[1][2][b][j] + partials[2][2][b][j] + partials[3][2][b][j] + ebr[1024 + jg];
      const float* gx = gxe + (size_t)(b * 512 + t) * 1536;
      float z = sigm(gx[jg] + g0);
      float r = sigm(gx[512 + jg] + g1);
      float c = tanh1(gx[1024 + jg] + r * g2);
      float hold = hcur[b * 512 + jg];
      float hnew = z * hold + (1.0f - z) * c;
      float hv = (etok[b * 512 + t] != 0) ? hnew : hold;
      hnxt[b * 512 + jg] = hv;
      eob[(size_t)(b * 512 + t) * 512 + jg] = f2bf(hv);
    }
    gbar(bars, 32);
  }
}

// Persistent decoder. grid=64 blocks.
// Phase A (blocks 0-31, jf=blk): q = h@W1+b1, ghd = h@dec_rk+br (MFMA, 4-wave K-split).
// Phase B (all, (b, e-quarter)): score=tanh(q+keys)·Va, p=exp(score), partial ctx & sum.
// Phase C (blocks 0-31): gctx = ctx_raw@dec_k_ctx (1/sum folded in), gates, masked h/out.
__global__ __launch_bounds__(256) void decoder_gru(
    const float* __restrict__ gxd,            // [B*TD][3H] = x@k_x + bi
    float* __restrict__ hbuf,                 // [2][B][H], buf0 = enc final state
    const unsigned short* __restrict__ keys_bf,  // [B*TE][H]
    const unsigned short* __restrict__ eob,   // [B*TE][H]
    const unsigned short* __restrict__ W1T,   // [H][H]
    const unsigned short* __restrict__ drkT,  // [3H][H]
    const unsigned short* __restrict__ dkT,   // [3H][H+E] (ctx part = cols 0..H)
    const float* __restrict__ b1, const float* __restrict__ dbr,
    const float* __restrict__ Va, const int* __restrict__ dtok,
    float* __restrict__ qg,                   // [B][H]
    float* __restrict__ ghd,                  // [B][3H]
    float* __restrict__ ctx_part,             // [4][B][H]
    float* __restrict__ sums_part,            // [B][4]
    unsigned short* __restrict__ dob,         // dec_out bf16 [B*TD][H]
    unsigned* __restrict__ bars) {
  __shared__ unsigned short keys_lds[128 * 512];  // swizzled
  __shared__ float partials[4][4][16][16];
  __shared__ float qlds[512];
  __shared__ float valds[512];
  __shared__ float plds[128];

  const int tid = threadIdx.x, lane = tid & 63, w = tid >> 6;
  const int blk = blockIdx.x;
  const int bB = blk >> 2, eq = blk & 3, e0 = eq * 128;
  const int jf = blk;  // valid when blk<32
  const f32x4 zz = {0.f, 0.f, 0.f, 0.f};

  // stage this block's keys slice (swizzled), Va
  for (int it = 0; it < 32; ++it) {
    int c = it * 256 + tid;
    int el = c >> 6, kb = c & 63;
    int sw = (kb * 8) ^ ((el & 7) << 3);
    *(uint4*)&keys_lds[el * 512 + sw] =
        *(const uint4*)(keys_bf + (size_t)(bB * 512 + e0 + el) * 512 + kb * 8);
  }
  valds[tid] = Va[tid];
  valds[tid + 256] = Va[tid + 256];

  for (int t = 0; t < 128; ++t) {
    const float* hcur = hbuf + (t & 1) * 8192;
    float* hnxt = hbuf + ((t & 1) ^ 1) * 8192;

    // ---------- Phase A ----------
    if (blk < 32) {
      f32x4 acc[4];
#pragma unroll
      for (int f = 0; f < 4; ++f) acc[f] = zz;
#pragma unroll
      for (int ks = 0; ks < 4; ++ks) {
        int kk = w * 128 + ks * 32 + ((lane >> 4) << 3);
        bf16x8_t af = cvt8(hcur + (lane & 15) * 512 + kk);
        bf16x8_t bq = *(const bf16x8_t*)(W1T + (size_t)(jf * 16 + (lane & 15)) * 512 + kk);
        acc[0] = MFMA16(af, bq, acc[0]);
#pragma unroll
        for (int g = 0; g < 3; ++g) {
          bf16x8_t bg = *(const bf16x8_t*)(drkT + (size_t)(g * 512 + jf * 16 + (lane & 15)) * 512 + kk);
          acc[1 + g] = MFMA16(af, bg, acc[1 + g]);
        }
      }
#pragma unroll
      for (int f = 0; f < 4; ++f)
#pragma unroll
        for (int r4 = 0; r4 < 4; ++r4)
          partials[w][f][(lane >> 4) * 4 + r4][lane & 15] = acc[f][r4];
    }
    __syncthreads();
    if (blk < 32) {
      int b = tid >> 4, j = tid & 15, jg = jf * 16 + j;
      float qv = partials[0][0][b][j] + partials[1][0][b][j] + partials[2][0][b][j] + partials[3][0][b][j] + b1[jg];
      qg[b * 512 + jg] = qv;
#pragma unroll
      for (int g = 0; g < 3; ++g) {
        float gv = partials[0][1 + g][b][j] + partials[1][1 + g][b][j] +
                   partials[2][1 + g][b][j] + partials[3][1 + g][b][j];
        ghd[b * 1536 + g * 512 + jg] = gv + dbr[g * 512 + jg];
      }
    }
    gbar(bars, 64);

    // ---------- Phase B ----------
    qlds[tid] = qg[bB * 512 + tid];
    qlds[tid + 256] = qg[bB * 512 + tid + 256];
    __syncthreads();
    {
      int el = tid >> 1, hh = (tid & 1) * 256;
      float pa = 0.0f, pb = 0.0f;
#pragma unroll 8
      for (int i = 0; i < 256; i += 2) {
        int uidx = el * 512 + ((hh + i) ^ ((el & 7) << 3));
        unsigned v = *(const unsigned*)&keys_lds[uidx];
        float k0 = bf2f((unsigned short)(v & 0xffffu));
        float k1 = bf2f((unsigned short)(v >> 16));
        pa += tanh1(qlds[hh + i] + k0) * valds[hh + i];
        pb += tanh1(qlds[hh + i + 1] + k1) * valds[hh + i + 1];
      }
      float part = pa + pb;
      float score = part + __shfl_xor(part, 1);
      float p = __expf(score);  // no max-subtract: |score| << 1, softmax invariant
      if ((tid & 1) == 0) plds[el] = p;
    }
    __syncthreads();
    if (tid < 64) {
      float s = plds[tid] + plds[tid + 64];
#pragma unroll
      for (int o = 32; o > 0; o >>= 1) s += __shfl_down(s, o);
      if (tid == 0) sums_part[bB * 4 + eq] = s;
    }
    {
      int h0 = tid * 2;
      float c0 = 0.0f, c1 = 0.0f;
      const unsigned short* ep = eob + (size_t)(bB * 512 + e0) * 512 + h0;
#pragma unroll 4
      for (int e = 0; e < 128; ++e) {
        float pw = plds[e];
        unsigned v = *(const unsigned*)(ep + (size_t)e * 512);
        c0 += pw * bf2f((unsigned short)(v & 0xffffu));
        c1 += pw * bf2f((unsigned short)(v >> 16));
      }
      ctx_part[(size_t)(eq * 16 + bB) * 512 + h0] = c0;
      ctx_part[(size_t)(eq * 16 + bB) * 512 + h0 + 1] = c1;
    }
    gbar(bars, 64);

    // ---------- Phase C ----------
    if (blk < 32) {
      f32x4 acc[3];
      acc[0] = zz; acc[1] = zz; acc[2] = zz;
#pragma unroll
      for (int ks = 0; ks < 4; ++ks) {
        int kk = w * 128 + ks * 32 + ((lane >> 4) << 3);
        float va[8];
#pragma unroll
        for (int i = 0; i < 8; ++i) va[i] = 0.f;
#pragma unroll
        for (int q = 0; q < 4; ++q) {
          const float* cp = ctx_part + (size_t)(q * 16 + (lane & 15)) * 512 + kk;
          float4 a = *(const float4*)cp;
          float4 b = *(const float4*)(cp + 4);
          va[0] += a.x; va[1] += a.y; va[2] += a.z; va[3] += a.w;
          va[4] += b.x; va[5] += b.y; va[6] += b.z; va[7] += b.w;
        }
        bf16x8_t af;
#pragma unroll
        for (int i = 0; i < 8; ++i) af[i] = bfr(va[i]);
#pragma unroll
        for (int g = 0; g < 3; ++g) {
          bf16x8_t bg = *(const bf16x8_t*)(dkT + (size_t)(g * 512 + jf * 16 + (lane & 15)) * 768 + kk);
          acc[g] = MFMA16(af, bg, acc[g]);
        }
      }
#pragma unroll
      for (int g = 0; g < 3; ++g)
#pragma unroll
        for (int r4 = 0; r4 < 4; ++r4)
          partials[w][g][(lane >> 4) * 4 + r4][lane & 15] = acc[g][r4];
    }
    __syncthreads();
    if (blk < 32) {
      int b = tid >> 4, j = tid & 15, jg = jf * 16 + j;
      float sden = sums_part[b * 4 + 0] + sums_part[b * 4 + 1] + sums_part[b * 4 + 2] + sums_part[b * 4 + 3];
      float sinv = 1.0f / sden;  // gctx = (ctx_raw@W)/sum  (linearity)
      float gc0 = (partials[0][0][b][j] + partials[1][0][b][j] + partials[2][0][b][j] + partials[3][0][b][j]) * sinv;
      float gc1 = (partials[0][1][b][j] + partials[1][1][b][j] + partials[2][1][b][j] + partials[3][1][b][j]) * sinv;
      float gc2 = (partials[0][2][b][j] + partials[1][2][b][j] + partials[2][2][b][j] + partials[3][2][b][j]) * sinv;
      const float* gx = gxd + (size_t)(b * 128 + t) * 1536;
      float hz = ghd[b * 1536 + jg];
      float hr = ghd[b * 1536 + 512 + jg];
      float hh2 = ghd[b * 1536 + 1024 + jg];
      float z = sigm(gx[jg] + gc0 + hz);
      float r = sigm(gx[512 + jg] + gc1 + hr);
      float cc = tanh1(gx[1024 + jg] + gc2 + r * hh2);
      float hold = hcur[b * 512 + jg];
      float hnew = z * hold + (1.0f - z) * cc;
      bool mm = dtok[b * 128 + t] != 0;
      float hv = mm ? hnew : hold;
      hnxt[b * 512 + jg] = hv;
      dob[(size_t)(b * 128 + t) * 512 + jg] = f2bf(mm ? hnew : 0.0f);
    }
    gbar(bars, 64);
  }
}

extern "C" void kernel_launch(void* const* d_in, const int* in_sizes, int n_in,
                              void* d_out, int out_size, void* d_ws, size_t ws_size,
                              hipStream_t stream) {
  (void)in_sizes; (void)n_in; (void)out_size; (void)ws_size;
  const int* enc_input = (const int*)d_in[0];
  const int* dec_input = (const int*)d_in[1];
  const float* embedding = (const float*)d_in[2];
  const float* enc_k = (const float*)d_in[3];
  const float* enc_rk = (const float*)d_in[4];
  const float* enc_bi = (const float*)d_in[5];
  const float* enc_br = (const float*)d_in[6];
  const float* dec_k = (const float*)d_in[7];
  const float* dec_rk = (const float*)d_in[8];
  const float* dec_bi = (const float*)d_in[9];
  const float* dec_br = (const float*)d_in[10];
  const float* W1 = (const float*)d_in[11];
  const float* b1 = (const float*)d_in[12];
  const float* W2 = (const float*)d_in[13];
  const float* b2 = (const float*)d_in[14];
  const float* Va = (const float*)d_in[15];
  const float* Wd = (const float*)d_in[17];
  const float* bd = (const float*)d_in[18];

  char* ws = (char*)d_ws;
  size_t off = 0;
  auto alloc = [&](size_t bytes) -> char* {
    char* p = ws + off;
    off += (bytes + 255) & ~(size_t)255;
    return p;
  };
  unsigned short* emb_bf  = (unsigned short*)alloc((size_t)VSZ * EDIM * 2);
  unsigned short* enc_kT  = (unsigned short*)alloc((size_t)G3H * EDIM * 2);
  unsigned short* enc_rkT = (unsigned short*)alloc((size_t)G3H * HDIM * 2);
  unsigned short* W1T     = (unsigned short*)alloc((size_t)HDIM * HDIM * 2);
  unsigned short* W2T     = (unsigned short*)alloc((size_t)HDIM * HDIM * 2);
  unsigned short* dec_kT  = (unsigned short*)alloc((size_t)G3H * (HDIM + EDIM) * 2);
  unsigned short* dec_rkT = (unsigned short*)alloc((size_t)G3H * HDIM * 2);
  unsigned short* WdT     = (unsigned short*)alloc((size_t)VSZ * HDIM * 2);
  unsigned short* eob     = (unsigned short*)alloc((size_t)BSZ * TEN * HDIM * 2);
  unsigned short* keys_bf = (unsigned short*)alloc((size_t)BSZ * TEN * HDIM * 2);
  unsigned short* dob     = (unsigned short*)alloc((size_t)BSZ * TDN * HDIM * 2);
  float* hbuf      = (float*)alloc((size_t)2 * BSZ * HDIM * 4);
  float* qg        = (float*)alloc((size_t)BSZ * HDIM * 4);
  float* ghd       = (float*)alloc((size_t)BSZ * G3H * 4);
  float* ctx_part  = (float*)alloc((size_t)4 * BSZ * HDIM * 4);
  float* sums_part = (float*)alloc((size_t)BSZ * 4 * 4);
  unsigned* bars   = (unsigned*)alloc(256);

  // d_out doubles as scratch for the big precomputed gate activations (dead before the
  // final logits GEMM overwrites the whole output).
  float* outp = (float*)d_out;
  float* gxe = outp;                               // [8192][1536]
  float* gxd = outp + (size_t)BSZ * TEN * G3H;     // [2048][1536]

  castP<<<2048, 256, 0, stream>>>(embedding, emb_bf, VSZ * EDIM / 4);
  castT<<<dim3(G3H / 32, EDIM / 32), 256, 0, stream>>>(enc_k, enc_kT, EDIM, G3H);
  castT<<<dim3(G3H / 32, HDIM / 32), 256, 0, stream>>>(enc_rk, enc_rkT, HDIM, G3H);
  castT<<<dim3(HDIM / 32, HDIM / 32), 256, 0, stream>>>(W1, W1T, HDIM, HDIM);
  castT<<<dim3(HDIM / 32, HDIM / 32), 256, 0, stream>>>(W2, W2T, HDIM, HDIM);
  castT<<<dim3(G3H / 32, (HDIM + EDIM) / 32), 256, 0, stream>>>(dec_k, dec_kT, HDIM + EDIM, G3H);
  castT<<<dim3(G3H / 32, HDIM / 32), 256, 0, stream>>>(dec_rk, dec_rkT, HDIM, G3H);
  castT<<<dim3(VSZ / 32, HDIM / 32), 256, 0, stream>>>(Wd, WdT, HDIM, VSZ);
  zerok<<<1, 64, 0, stream>>>(bars, 64);

  // gxe = emb[enc_input] @ enc_k + enc_bi
  gemm_bf16<true, false><<<dim3(G3H / 128, BSZ * TEN / 128), 256, 0, stream>>>(
      emb_bf, enc_input, enc_kT, enc_bi, gxe, BSZ * TEN, G3H, EDIM, EDIM, EDIM);
  // encoder recurrence
  encoder_gru<<<32, 256, 0, stream>>>(gxe, enc_rkT, enc_input, enc_br, hbuf, eob, bars);
  // keys = enc_out @ W2 + b2 (bf16 out)
  gemm_bf16<false, true><<<dim3(HDIM / 128, BSZ * TEN / 128), 256, 0, stream>>>(
      eob, nullptr, W2T, b2, keys_bf, BSZ * TEN, HDIM, HDIM, HDIM, HDIM);
  // gxd = emb[dec_input] @ dec_k[H:] + dec_bi
  gemm_bf16<true, false><<<dim3(G3H / 128, BSZ * TDN / 128), 256, 0, stream>>>(
      emb_bf, dec_input, dec_kT + HDIM, dec_bi, gxd, BSZ * TDN, G3H, EDIM, EDIM, HDIM + EDIM);
  // decoder recurrence + attention
  decoder_gru<<<64, 256, 0, stream>>>(gxd, hbuf, keys_bf, eob, W1T, dec_rkT, dec_kT,
                                      b1, dec_br, Va, dec_input, qg, ghd, ctx_part,
                                      sums_part, dob, bars + 16);
  // logits = dec_out @ Wd + bd
  gemm_bf16<false, false><<<dim3(VSZ / 128, BSZ * TDN / 128), 256, 0, stream>>>(
      dob, nullptr, WdT, bd, outp, BSZ * TDN, VSZ, HDIM, HDIM, HDIM);
}

// Round 2
// 6911.335 us; speedup vs baseline: 2.0430x; 2.0430x over previous
//
#include <hip/hip_runtime.h>

#define DEV __device__ __forceinline__

typedef float f32x4 __attribute__((ext_vector_type(4)));
typedef __bf16 bf16x8_t __attribute__((ext_vector_type(8)));

#define VSZ 32000
#define EDIM 256
#define HDIM 512
#define BSZ 16
#define TEN 512
#define TDN 128
#define G3H 1536

#define NCMP 32
#define NATT 128
#define WP 520   // weight LDS pitch (halfwords)
#define KP 524   // keys LDS pitch (halfwords)

DEV unsigned short f2bf(float f) {
  unsigned u = __builtin_bit_cast(unsigned, f);
  return (unsigned short)((u + 0x7fffu + ((u >> 16) & 1u)) >> 16);
}
DEV float bf2f(unsigned short s) {
  unsigned u = ((unsigned)s) << 16;
  return __builtin_bit_cast(float, u);
}
DEV __bf16 bfr(float f) {
  unsigned short s = f2bf(f);
  return __builtin_bit_cast(__bf16, s);
}
DEV bf16x8_t cvt8(const float* p) {
  float4 a = *(const float4*)p;
  float4 b = *(const float4*)(p + 4);
  bf16x8_t r;
  r[0] = bfr(a.x); r[1] = bfr(a.y); r[2] = bfr(a.z); r[3] = bfr(a.w);
  r[4] = bfr(b.x); r[5] = bfr(b.y); r[6] = bfr(b.z); r[7] = bfr(b.w);
  return r;
}
DEV float sigm(float x) { return __builtin_amdgcn_rcpf(1.0f + __expf(-x)); }
DEV float tanh1(float x) { return 1.0f - 2.0f * __builtin_amdgcn_rcpf(__expf(2.0f * x) + 1.0f); }

#define MFMA16(a, b, c) __builtin_amdgcn_mfma_f32_16x16x32_bf16((a), (b), (c), 0, 0, 0)

// ---- distributed flag sync (no central RMW) ----
DEV void set_flag(unsigned* f, unsigned gen) {
  __syncthreads();  // all block stores drained to L2 (compiler emits vmcnt(0) per thread)
  if (threadIdx.x == 0) {
    __builtin_amdgcn_fence(__ATOMIC_RELEASE, "agent");  // wbl2: publish L2 -> coherent point
    __hip_atomic_store(f, gen, __ATOMIC_RELAXED, __HIP_MEMORY_SCOPE_AGENT);
  }
}
DEV void wait_flags(unsigned* f, int n, unsigned gen) {
  int tid = threadIdx.x;
  if (tid < n) {
    while (__hip_atomic_load(f + tid, __ATOMIC_RELAXED, __HIP_MEMORY_SCOPE_AGENT) < gen)
      __builtin_amdgcn_s_sleep(1);
  }
  __syncthreads();
  __builtin_amdgcn_fence(__ATOMIC_ACQUIRE, "agent");  // inv L1/L2: see producers' data
}

__global__ void zerok(unsigned* p, int n) {
  int i = blockIdx.x * blockDim.x + threadIdx.x;
  if (i < n) p[i] = 0u;
}

// fp32 -> bf16, same layout
__global__ __launch_bounds__(256) void castP(const float* __restrict__ in,
                                             unsigned short* __restrict__ out, int n4) {
  int i = blockIdx.x * blockDim.x + threadIdx.x;
  int stride = gridDim.x * blockDim.x;
  for (; i < n4; i += stride) {
    float4 v = ((const float4*)in)[i];
    ushort4 o;
    o.x = f2bf(v.x); o.y = f2bf(v.y); o.z = f2bf(v.z); o.w = f2bf(v.w);
    ((ushort4*)out)[i] = o;
  }
}

// fp32 [K][N] -> bf16 [N][K] (transpose)
__global__ __launch_bounds__(256) void castT(const float* __restrict__ in,
                                             unsigned short* __restrict__ out, int K, int N) {
  __shared__ unsigned short tile[32][33];
  int tx = threadIdx.x & 31, ty = threadIdx.x >> 5;
  int bx = blockIdx.x, by = blockIdx.y;
  for (int i = ty; i < 32; i += 8)
    tile[i][tx] = f2bf(in[(size_t)(by * 32 + i) * N + bx * 32 + tx]);
  __syncthreads();
  for (int i = ty; i < 32; i += 8)
    out[(size_t)(bx * 32 + i) * K + by * 32 + tx] = tile[tx][i];
}

// C[M][N] (f32 or bf16) = A[M][K]bf16 (optional row gather) @ BT[N][K]bf16 + bias[N]
template <bool GATHER, bool OUTBF>
__global__ __launch_bounds__(256) void gemm_bf16(
    const unsigned short* __restrict__ A, const int* __restrict__ tok,
    const unsigned short* __restrict__ BT, const float* __restrict__ bias,
    void* __restrict__ Cout, int M, int N, int K, int lda, int ldb) {
  __shared__ unsigned short As[128][72];
  __shared__ unsigned short Bs[128][72];
  const int tid = threadIdx.x;
  const int lane = tid & 63, w = tid >> 6;
  const int wr = w >> 1, wc = w & 1;
  const int m0 = blockIdx.y * 128, n0 = blockIdx.x * 128;

  const f32x4 zz = {0.f, 0.f, 0.f, 0.f};
  f32x4 acc[4][4];
#pragma unroll
  for (int i = 0; i < 4; ++i)
#pragma unroll
    for (int j = 0; j < 4; ++j) acc[i][j] = zz;

  for (int kt = 0; kt < K; kt += 64) {
#pragma unroll
    for (int it = 0; it < 4; ++it) {
      int c = it * 256 + tid;
      int row = c >> 3, kb = c & 7;
      size_t arow = GATHER ? (size_t)tok[m0 + row] : (size_t)(m0 + row);
      *(uint4*)&As[row][kb * 8] = *(const uint4*)(A + arow * lda + kt + kb * 8);
      *(uint4*)&Bs[row][kb * 8] = *(const uint4*)(BT + (size_t)(n0 + row) * ldb + kt + kb * 8);
    }
    __syncthreads();
#pragma unroll
    for (int ks = 0; ks < 2; ++ks) {
      int kk = ks * 32 + ((lane >> 4) << 3);
      bf16x8_t af[4], bg[4];
#pragma unroll
      for (int fm = 0; fm < 4; ++fm)
        af[fm] = *(const bf16x8_t*)&As[wr * 64 + fm * 16 + (lane & 15)][kk];
#pragma unroll
      for (int fn = 0; fn < 4; ++fn)
        bg[fn] = *(const bf16x8_t*)&Bs[wc * 64 + fn * 16 + (lane & 15)][kk];
#pragma unroll
      for (int fm = 0; fm < 4; ++fm)
#pragma unroll
        for (int fn = 0; fn < 4; ++fn)
          acc[fm][fn] = MFMA16(af[fm], bg[fn], acc[fm][fn]);
    }
    __syncthreads();
  }
#pragma unroll
  for (int fn = 0; fn < 4; ++fn) {
    int n = n0 + wc * 64 + fn * 16 + (lane & 15);
    float bv = bias[n];
#pragma unroll
    for (int fm = 0; fm < 4; ++fm) {
      int mb = m0 + wr * 64 + fm * 16 + ((lane >> 4) << 2);
#pragma unroll
      for (int j = 0; j < 4; ++j) {
        float v = acc[fm][fn][j] + bv;
        if (OUTBF)
          ((unsigned short*)Cout)[(size_t)(mb + j) * N + n] = f2bf(v);
        else
          ((float*)Cout)[(size_t)(mb + j) * N + n] = v;
      }
    }
  }
}

// Persistent encoder GRU. 32 blocks, block jf owns h cols [jf*16, jf*16+16).
__global__ __launch_bounds__(256) void encoder_gru(
    const float* __restrict__ gxe, const unsigned short* __restrict__ rkT,
    const int* __restrict__ etok, const float* __restrict__ ebr,
    float* __restrict__ hbuf, unsigned short* __restrict__ eob,
    unsigned* __restrict__ flags) {
  __shared__ unsigned short wlds[48][WP];
  __shared__ float partials[4][3][16][16];
  __shared__ float ebrl[48];
  const int tid = threadIdx.x, lane = tid & 63, w = tid >> 6;
  const int jf = blockIdx.x;
  const f32x4 zz = {0.f, 0.f, 0.f, 0.f};

  for (int idx = tid; idx < 3072; idx += 256) {
    int r = idx >> 6, kb = idx & 63;
    int g = r >> 4, jj = r & 15;
    *(uint4*)&wlds[r][kb * 8] =
        *(const uint4*)(rkT + (size_t)(g * 512 + jf * 16 + jj) * 512 + kb * 8);
  }
  if (tid < 48) ebrl[tid] = ebr[(tid >> 4) * 512 + jf * 16 + (tid & 15)];
  { int b = tid >> 4, j = tid & 15; hbuf[b * 512 + jf * 16 + j] = 0.0f; }
  unsigned gen = 1;
  set_flag(flags + jf, gen);
  wait_flags(flags, NCMP, gen);

  const int rb = tid >> 4, rj = tid & 15, rjg = jf * 16 + rj;
  for (int t = 0; t < TEN; ++t) {
    const float* hcur = hbuf + (t & 1) * 8192;
    float* hnxt = hbuf + ((t & 1) ^ 1) * 8192;
    // prefetch gate inputs (independent of h MFMA)
    const float* gx = gxe + (size_t)(rb * 512 + t) * 1536;
    float gx0 = gx[rjg], gx1 = gx[512 + rjg], gx2 = gx[1024 + rjg];
    int tkv = etok[rb * 512 + t];
    float hold = hcur[rb * 512 + rjg];

    f32x4 a0 = zz, a1 = zz, a2 = zz;
#pragma unroll
    for (int ks = 0; ks < 4; ++ks) {
      int kk = w * 128 + ks * 32 + ((lane >> 4) << 3);
      bf16x8_t af = cvt8(hcur + (lane & 15) * 512 + kk);
      a0 = MFMA16(af, *(const bf16x8_t*)&wlds[(lane & 15)][kk], a0);
      a1 = MFMA16(af, *(const bf16x8_t*)&wlds[16 + (lane & 15)][kk], a1);
      a2 = MFMA16(af, *(const bf16x8_t*)&wlds[32 + (lane & 15)][kk], a2);
    }
#pragma unroll
    for (int r4 = 0; r4 < 4; ++r4) {
      partials[w][0][(lane >> 4) * 4 + r4][lane & 15] = a0[r4];
      partials[w][1][(lane >> 4) * 4 + r4][lane & 15] = a1[r4];
      partials[w][2][(lane >> 4) * 4 + r4][lane & 15] = a2[r4];
    }
    __syncthreads();
    {
      float g0 = partials[0][0][rb][rj] + partials[1][0][rb][rj] +
                 partials[2][0][rb][rj] + partials[3][0][rb][rj] + ebrl[rj];
      float g1 = partials[0][1][rb][rj] + partials[1][1][rb][rj] +
                 partials[2][1][rb][rj] + partials[3][1][rb][rj] + ebrl[16 + rj];
      float g2 = partials[0][2][rb][rj] + partials[1][2][rb][rj] +
                 partials[2][2][rb][rj] + partials[3][2][rb][rj] + ebrl[32 + rj];
      float z = sigm(gx0 + g0);
      float r = sigm(gx1 + g1);
      float c = tanh1(gx2 + r * g2);
      float hnew = z * hold + (1.0f - z) * c;
      float hv = (tkv != 0) ? hnew : hold;
      hnxt[rb * 512 + rjg] = hv;
      eob[(size_t)(rb * 512 + t) * 512 + rjg] = f2bf(hv);
    }
    ++gen;
    set_flag(flags + jf, gen);
    wait_flags(flags, NCMP, gen);
  }
}

// Persistent decoder: 160 blocks.
//  blocks [0,32):  compute blocks, jf = blk; weights LDS-resident.
//    per step: wait flagC>=t; A: q,gh from h; set flagA=t+1; wait flagB>=t+1;
//              C: gctx from ctx partials, gates, h update; set flagC=t+1.
//  blocks [32,160): attention blocks, ab=blk-32 -> (b = ab>>3, e-slice = ab&7), 64 keys each.
//    per step: wait flagA>=t+1; B: scores=tanh, softmax partials, ctx partials; set flagB=t+1.
__global__ __launch_bounds__(256) void decoder_gru(
    const float* __restrict__ gxd, float* __restrict__ hbuf,
    const unsigned short* __restrict__ keys_bf, const unsigned short* __restrict__ eob,
    const unsigned short* __restrict__ W1T, const unsigned short* __restrict__ drkT,
    const unsigned short* __restrict__ dkT,
    const float* __restrict__ b1, const float* __restrict__ dbr,
    const float* __restrict__ Va, const int* __restrict__ dtok,
    float* __restrict__ qg, float* __restrict__ ctx_part, float* __restrict__ sums_part,
    unsigned short* __restrict__ dob,
    unsigned* __restrict__ flagA, unsigned* __restrict__ flagB, unsigned* __restrict__ flagC) {
  __shared__ __align__(16) char smem[138752];
  const int tid = threadIdx.x, lane = tid & 63, w = tid >> 6;
  const int blk = blockIdx.x;
  const f32x4 zz = {0.f, 0.f, 0.f, 0.f};

  if (blk < NCMP) {
    // ---------------- compute block ----------------
    const int jf = blk;
    unsigned short* w1l = (unsigned short*)smem;   // 16 x WP
    unsigned short* drl = w1l + 16 * WP;           // 48 x WP
    unsigned short* dkl = drl + 48 * WP;           // 48 x WP
    float* partials = (float*)(smem + 2 * 112 * WP);  // [4][4][16][16]
    float* ghl = partials + 4096;                  // [3][16][16]
    float* sinvl = ghl + 768;                      // [16]
    float* cbias = sinvl + 16;                     // [64]: b1 slice + dbr 3x16

    for (int idx = tid; idx < 1024; idx += 256) {
      int r = idx >> 6, kb = idx & 63;
      *(uint4*)&w1l[r * WP + kb * 8] =
          *(const uint4*)(W1T + (size_t)(jf * 16 + r) * 512 + kb * 8);
    }
    for (int idx = tid; idx < 3072; idx += 256) {
      int r = idx >> 6, kb = idx & 63;
      int g = r >> 4, jj = r & 15;
      *(uint4*)&drl[r * WP + kb * 8] =
          *(const uint4*)(drkT + (size_t)(g * 512 + jf * 16 + jj) * 512 + kb * 8);
      *(uint4*)&dkl[r * WP + kb * 8] =
          *(const uint4*)(dkT + (size_t)(g * 512 + jf * 16 + jj) * 768 + kb * 8);
    }
    if (tid < 16) cbias[tid] = b1[jf * 16 + tid];
    if (tid < 48) cbias[16 + tid] = dbr[(tid >> 4) * 512 + jf * 16 + (tid & 15)];
    const int rb = tid >> 4, rj = tid & 15, rjg = jf * 16 + rj;

    for (int t = 0; t < TDN; ++t) {
      wait_flags(flagC, NCMP, (unsigned)t);  // C_{t-1} done everywhere (t=0 trivial)
      const float* hcur = hbuf + (t & 1) * 8192;
      float* hnxt = hbuf + ((t & 1) ^ 1) * 8192;
      float hold = hcur[rb * 512 + rjg];

      // ---- Phase A: q = h@W1+b1 (x2 pre-scale), gh = h@dec_rk+br ----
      f32x4 a0 = zz, a1 = zz, a2 = zz, a3 = zz;
#pragma unroll
      for (int ks = 0; ks < 4; ++ks) {
        int kk = w * 128 + ks * 32 + ((lane >> 4) << 3);
        bf16x8_t af = cvt8(hcur + (lane & 15) * 512 + kk);
        a0 = MFMA16(af, *(const bf16x8_t*)&w1l[(lane & 15) * WP + kk], a0);
        a1 = MFMA16(af, *(const bf16x8_t*)&drl[(lane & 15) * WP + kk], a1);
        a2 = MFMA16(af, *(const bf16x8_t*)&drl[(16 + (lane & 15)) * WP + kk], a2);
        a3 = MFMA16(af, *(const bf16x8_t*)&drl[(32 + (lane & 15)) * WP + kk], a3);
      }
#pragma unroll
      for (int r4 = 0; r4 < 4; ++r4) {
        int rr = (lane >> 4) * 4 + r4, cc = lane & 15;
        partials[((w * 4 + 0) * 16 + rr) * 16 + cc] = a0[r4];
        partials[((w * 4 + 1) * 16 + rr) * 16 + cc] = a1[r4];
        partials[((w * 4 + 2) * 16 + rr) * 16 + cc] = a2[r4];
        partials[((w * 4 + 3) * 16 + rr) * 16 + cc] = a3[r4];
      }
      __syncthreads();
      {
#define PRD(f) (partials[((0 * 4 + (f)) * 16 + rb) * 16 + rj] + \
                partials[((1 * 4 + (f)) * 16 + rb) * 16 + rj] + \
                partials[((2 * 4 + (f)) * 16 + rb) * 16 + rj] + \
                partials[((3 * 4 + (f)) * 16 + rb) * 16 + rj])
        float qv = PRD(0) + cbias[rj];
        qg[rb * 512 + rjg] = qv * 2.0f;  // pre-scaled for exp(2x) form of tanh
        ghl[0 * 256 + rb * 16 + rj] = PRD(1) + cbias[16 + rj];
        ghl[1 * 256 + rb * 16 + rj] = PRD(2) + cbias[32 + rj];
        ghl[2 * 256 + rb * 16 + rj] = PRD(3) + cbias[48 + rj];
      }
      set_flag(flagA + jf, (unsigned)(t + 1));
      wait_flags(flagB, NATT, (unsigned)(t + 1));

      // ---- Phase C: gctx = (sum ctx partials / sum p) @ dec_k_ctx; gates ----
      const float* gx = gxd + (size_t)(rb * 128 + t) * 1536;  // prefetch (hides L3 latency)
      float gx0 = gx[rjg], gx1 = gx[512 + rjg], gx2 = gx[1024 + rjg];
      int tkv = dtok[rb * 128 + t];
      if (tid < 16) {
        const float* sp = sums_part + tid * 8;
        sinvl[tid] = 1.0f / (sp[0] + sp[1] + sp[2] + sp[3] + sp[4] + sp[5] + sp[6] + sp[7]);
      }
      __syncthreads();
      float sv = sinvl[lane & 15];
      f32x4 c0 = zz, c1 = zz, c2 = zz;
#pragma unroll
      for (int ks = 0; ks < 4; ++ks) {
        int kk = w * 128 + ks * 32 + ((lane >> 4) << 3);
        float va8[8];
#pragma unroll
        for (int i = 0; i < 8; ++i) va8[i] = 0.f;
#pragma unroll
        for (int q = 0; q < 8; ++q) {
          const float* cp = ctx_part + (size_t)((lane & 15) * 8 + q) * 512 + kk;
          float4 x = *(const float4*)cp;
          float4 y = *(const float4*)(cp + 4);
          va8[0] += x.x; va8[1] += x.y; va8[2] += x.z; va8[3] += x.w;
          va8[4] += y.x; va8[5] += y.y; va8[6] += y.z; va8[7] += y.w;
        }
        bf16x8_t af;
#pragma unroll
        for (int i = 0; i < 8; ++i) af[i] = bfr(va8[i] * sv);
        c0 = MFMA16(af, *(const bf16x8_t*)&dkl[(lane & 15) * WP + kk], c0);
        c1 = MFMA16(af, *(const bf16x8_t*)&dkl[(16 + (lane & 15)) * WP + kk], c1);
        c2 = MFMA16(af, *(const bf16x8_t*)&dkl[(32 + (lane & 15)) * WP + kk], c2);
      }
#pragma unroll
      for (int r4 = 0; r4 < 4; ++r4) {
        int rr = (lane >> 4) * 4 + r4, cc = lane & 15;
        partials[((w * 4 + 0) * 16 + rr) * 16 + cc] = c0[r4];
        partials[((w * 4 + 1) * 16 + rr) * 16 + cc] = c1[r4];
        partials[((w * 4 + 2) * 16 + rr) * 16 + cc] = c2[r4];
      }
      __syncthreads();
      {
        float gc0 = PRD(0), gc1 = PRD(1), gc2 = PRD(2);
        float z = sigm(gx0 + gc0 + ghl[rb * 16 + rj]);
        float r = sigm(gx1 + gc1 + ghl[256 + rb * 16 + rj]);
        float cc2 = tanh1(gx2 + gc2 + r * ghl[512 + rb * 16 + rj]);
        float hnew = z * hold + (1.0f - z) * cc2;
        float hv = (tkv != 0) ? hnew : hold;
        hnxt[rb * 512 + rjg] = hv;
        dob[(size_t)(rb * 128 + t) * 512 + rjg] = f2bf((tkv != 0) ? hnew : 0.0f);
#undef PRD
      }
      set_flag(flagC + jf, (unsigned)(t + 1));
    }
  } else {
    // ---------------- attention block ----------------
    const int ab = blk - NCMP, bB = ab >> 3, eq = ab & 7, e0 = eq * 64;
    unsigned short* kl = (unsigned short*)smem;   // 64 x KP (keys*2, bf16)
    unsigned short* el_ = kl + 64 * KP;           // 64 x 512 (enc_out bf16)
    float* qlds = (float*)(el_ + 64 * 512);       // [512]
    float* valds = qlds + 512;                    // [512]
    float* plds = valds + 512;                    // [64]

    for (int idx = tid; idx < 4096; idx += 256) {  // 64 rows x 64 chunks of 8 halfwords
      int el = idx >> 6, kb = idx & 63;
      uint4 v = *(const uint4*)(keys_bf + (size_t)(bB * 512 + e0 + el) * 512 + kb * 8);
      const unsigned short* sp = (const unsigned short*)&v;
      unsigned short tmp[8];
#pragma unroll
      for (int i = 0; i < 8; ++i) tmp[i] = f2bf(bf2f(sp[i]) * 2.0f);  // exact x2
      *(uint2*)&kl[el * KP + kb * 8] = *(uint2*)&tmp[0];
      *(uint2*)&kl[el * KP + kb * 8 + 4] = *(uint2*)&tmp[4];
      uint4 e2 = *(const uint4*)(eob + (size_t)(bB * 512 + e0 + el) * 512 + kb * 8);
      *(uint4*)&el_[el * 512 + kb * 8] = e2;
    }
    valds[tid] = Va[tid];
    valds[tid + 256] = Va[tid + 256];
    __syncthreads();
    const int elr = tid >> 2, hh = (tid & 3) * 128;
    float sva = 0.f;
    for (int i = 0; i < 128; ++i) sva += valds[hh + i];

    for (int t = 0; t < TDN; ++t) {
      wait_flags(flagA, NCMP, (unsigned)(t + 1));
      qlds[tid] = qg[bB * 512 + tid];
      qlds[tid + 256] = qg[bB * 512 + tid + 256];
      __syncthreads();
      // score = Va . tanh(q + keys) ; tanh(x) = 1 - 2/(exp(2x)+1), args pre-scaled x2
      float ra = 0.f, rb2 = 0.f;
#pragma unroll 8
      for (int i = 0; i < 128; i += 2) {
        unsigned kv = *(const unsigned*)&kl[elr * KP + hh + i];
        float s0 = qlds[hh + i] + bf2f((unsigned short)(kv & 0xffffu));
        float s1 = qlds[hh + i + 1] + bf2f((unsigned short)(kv >> 16));
        ra = fmaf(valds[hh + i], __builtin_amdgcn_rcpf(__expf(s0) + 1.0f), ra);
        rb2 = fmaf(valds[hh + i + 1], __builtin_amdgcn_rcpf(__expf(s1) + 1.0f), rb2);
      }
      float part = sva - 2.0f * (ra + rb2);
      part += __shfl_xor(part, 1);
      part += __shfl_xor(part, 2);
      float p = __expf(part);  // no max-subtract: |score| small, softmax invariant
      if ((tid & 3) == 0) plds[elr] = p;
      __syncthreads();
      if (tid < 64) {
        float s = plds[tid];
#pragma unroll
        for (int o = 32; o > 0; o >>= 1) s += __shfl_down(s, o);
        if (tid == 0) sums_part[bB * 8 + eq] = s;
      }
      {
        int h0 = tid * 2;
        float cc0 = 0.f, cc1 = 0.f;
#pragma unroll 4
        for (int e = 0; e < 64; ++e) {
          float pw = plds[e];
          unsigned v = *(const unsigned*)&el_[e * 512 + h0];
          cc0 = fmaf(pw, bf2f((unsigned short)(v & 0xffffu)), cc0);
          cc1 = fmaf(pw, bf2f((unsigned short)(v >> 16)), cc1);
        }
        ctx_part[(size_t)ab * 512 + h0] = cc0;
        ctx_part[(size_t)ab * 512 + h0 + 1] = cc1;
      }
      set_flag(flagB + ab, (unsigned)(t + 1));
    }
  }
}

extern "C" void kernel_launch(void* const* d_in, const int* in_sizes, int n_in,
                              void* d_out, int out_size, void* d_ws, size_t ws_size,
                              hipStream_t stream) {
  (void)in_sizes; (void)n_in; (void)out_size; (void)ws_size;
  const int* enc_input = (const int*)d_in[0];
  const int* dec_input = (const int*)d_in[1];
  const float* embedding = (const float*)d_in[2];
  const float* enc_k = (const float*)d_in[3];
  const float* enc_rk = (const float*)d_in[4];
  const float* enc_bi = (const float*)d_in[5];
  const float* enc_br = (const float*)d_in[6];
  const float* dec_k = (const float*)d_in[7];
  const float* dec_rk = (const float*)d_in[8];
  const float* dec_bi = (const float*)d_in[9];
  const float* dec_br = (const float*)d_in[10];
  const float* W1 = (const float*)d_in[11];
  const float* b1 = (const float*)d_in[12];
  const float* W2 = (const float*)d_in[13];
  const float* b2 = (const float*)d_in[14];
  const float* Va = (const float*)d_in[15];
  const float* Wd = (const float*)d_in[17];
  const float* bd = (const float*)d_in[18];

  char* ws = (char*)d_ws;
  size_t off = 0;
  auto alloc = [&](size_t bytes) -> char* {
    char* p = ws + off;
    off += (bytes + 255) & ~(size_t)255;
    return p;
  };
  unsigned short* emb_bf  = (unsigned short*)alloc((size_t)VSZ * EDIM * 2);
  unsigned short* enc_kT  = (unsigned short*)alloc((size_t)G3H * EDIM * 2);
  unsigned short* enc_rkT = (unsigned short*)alloc((size_t)G3H * HDIM * 2);
  unsigned short* W1T     = (unsigned short*)alloc((size_t)HDIM * HDIM * 2);
  unsigned short* W2T     = (unsigned short*)alloc((size_t)HDIM * HDIM * 2);
  unsigned short* dec_kT  = (unsigned short*)alloc((size_t)G3H * (HDIM + EDIM) * 2);
  unsigned short* dec_rkT = (unsigned short*)alloc((size_t)G3H * HDIM * 2);
  unsigned short* WdT     = (unsigned short*)alloc((size_t)VSZ * HDIM * 2);
  unsigned short* eob     = (unsigned short*)alloc((size_t)BSZ * TEN * HDIM * 2);
  unsigned short* keys_bf = (unsigned short*)alloc((size_t)BSZ * TEN * HDIM * 2);
  unsigned short* dob     = (unsigned short*)alloc((size_t)BSZ * TDN * HDIM * 2);
  float* hbuf      = (float*)alloc((size_t)2 * BSZ * HDIM * 4);
  float* qg        = (float*)alloc((size_t)BSZ * HDIM * 4);
  float* ctx_part  = (float*)alloc((size_t)NATT * HDIM * 4);
  float* sums_part = (float*)alloc((size_t)BSZ * 8 * 4);
  unsigned* bars   = (unsigned*)alloc(1024);

  // d_out doubles as scratch for the precomputed input-gate activations (dead
  // before the final logits GEMM overwrites the whole output).
  float* outp = (float*)d_out;
  float* gxe = outp;                               // [8192][1536]
  float* gxd = outp + (size_t)BSZ * TEN * G3H;     // [2048][1536]

  castP<<<2048, 256, 0, stream>>>(embedding, emb_bf, VSZ * EDIM / 4);
  castT<<<dim3(G3H / 32, EDIM / 32), 256, 0, stream>>>(enc_k, enc_kT, EDIM, G3H);
  castT<<<dim3(G3H / 32, HDIM / 32), 256, 0, stream>>>(enc_rk, enc_rkT, HDIM, G3H);
  castT<<<dim3(HDIM / 32, HDIM / 32), 256, 0, stream>>>(W1, W1T, HDIM, HDIM);
  castT<<<dim3(HDIM / 32, HDIM / 32), 256, 0, stream>>>(W2, W2T, HDIM, HDIM);
  castT<<<dim3(G3H / 32, (HDIM + EDIM) / 32), 256, 0, stream>>>(dec_k, dec_kT, HDIM + EDIM, G3H);
  castT<<<dim3(G3H / 32, HDIM / 32), 256, 0, stream>>>(dec_rk, dec_rkT, HDIM, G3H);
  castT<<<dim3(VSZ / 32, HDIM / 32), 256, 0, stream>>>(Wd, WdT, HDIM, VSZ);
  zerok<<<1, 256, 0, stream>>>(bars, 256);

  // gxe = emb[enc_input] @ enc_k + enc_bi
  gemm_bf16<true, false><<<dim3(G3H / 128, BSZ * TEN / 128), 256, 0, stream>>>(
      emb_bf, enc_input, enc_kT, enc_bi, gxe, BSZ * TEN, G3H, EDIM, EDIM, EDIM);
  // encoder recurrence
  encoder_gru<<<NCMP, 256, 0, stream>>>(gxe, enc_rkT, enc_input, enc_br, hbuf, eob, bars);
  // keys = enc_out @ W2 + b2 (bf16 out)
  gemm_bf16<false, true><<<dim3(HDIM / 128, BSZ * TEN / 128), 256, 0, stream>>>(
      eob, nullptr, W2T, b2, keys_bf, BSZ * TEN, HDIM, HDIM, HDIM, HDIM);
  // gxd = emb[dec_input] @ dec_k[H:] + dec_bi
  gemm_bf16<true, false><<<dim3(G3H / 128, BSZ * TDN / 128), 256, 0, stream>>>(
      emb_bf, dec_input, dec_kT + HDIM, dec_bi, gxd, BSZ * TDN, G3H, EDIM, EDIM, HDIM + EDIM);
  // decoder recurrence + attention (32 compute + 128 attention blocks)
  decoder_gru<<<NCMP + NATT, 256, 0, stream>>>(
      gxd, hbuf, keys_bf, eob, W1T, dec_rkT, dec_kT, b1, dec_br, Va, dec_input,
      qg, ctx_part, sums_part, dob, bars + 32, bars + 64, bars + 192);
  // logits = dec_out @ Wd + bd
  gemm_bf16<false, false><<<dim3(VSZ / 128, BSZ * TDN / 128), 256, 0, stream>>>(
      dob, nullptr, WdT, bd, outp, BSZ * TDN, VSZ, HDIM, HDIM, HDIM);
}

// Round 5
// 6421.946 us; speedup vs baseline: 2.1987x; 1.0762x over previous
//
#include <hip/hip_runtime.h>

#define DEV __device__ __forceinline__

typedef float f32x4 __attribute__((ext_vector_type(4)));
typedef __bf16 bf16x8_t __attribute__((ext_vector_type(8)));

#define VSZ 32000
#define EDIM 256
#define HDIM 512
#define BSZ 16
#define TEN 512
#define TDN 128
#define G3H 1536

#define NCMP 32
#define NATT 128
#define WP 520   // weight LDS pitch (halfwords)
#define KP 524   // keys LDS pitch (halfwords)

DEV unsigned short f2bf(float f) {
  unsigned u = __builtin_bit_cast(unsigned, f);
  return (unsigned short)((u + 0x7fffu + ((u >> 16) & 1u)) >> 16);
}
DEV float bf2f(unsigned short s) {
  unsigned u = ((unsigned)s) << 16;
  return __builtin_bit_cast(float, u);
}
DEV __bf16 bfr(float f) {
  unsigned short s = f2bf(f);
  return __builtin_bit_cast(__bf16, s);
}
DEV float sigm(float x) { return __builtin_amdgcn_rcpf(1.0f + __expf(-x)); }
DEV float tanh1(float x) { return 1.0f - 2.0f * __builtin_amdgcn_rcpf(__expf(2.0f * x) + 1.0f); }

#define MFMA16(a, b, c) __builtin_amdgcn_mfma_f32_16x16x32_bf16((a), (b), (c), 0, 0, 0)

// ---- coherent-point data access (bypass L1/L2; no fences ever needed) ----
DEV float ald1(const float* p) {
  unsigned v = __hip_atomic_load((const unsigned*)p, __ATOMIC_RELAXED, __HIP_MEMORY_SCOPE_AGENT);
  return __builtin_bit_cast(float, v);
}
DEV void ast1(float* p, float x) {
  __hip_atomic_store((unsigned*)p, __builtin_bit_cast(unsigned, x), __ATOMIC_RELAXED,
                     __HIP_MEMORY_SCOPE_AGENT);
}
DEV float2 ald2(const float* p) {
  unsigned long long v = __hip_atomic_load((const unsigned long long*)p, __ATOMIC_RELAXED,
                                           __HIP_MEMORY_SCOPE_AGENT);
  return __builtin_bit_cast(float2, v);
}
DEV void ast2(float* p, float x, float y) {
  float2 t; t.x = x; t.y = y;
  __hip_atomic_store((unsigned long long*)p, __builtin_bit_cast(unsigned long long, t),
                     __ATOMIC_RELAXED, __HIP_MEMORY_SCOPE_AGENT);
}
DEV bf16x8_t cvt8a(const float* p) {  // 8 fp32 (coherent) -> bf16x8
  float2 a = ald2(p), b = ald2(p + 2), c = ald2(p + 4), d = ald2(p + 6);
  bf16x8_t r;
  r[0] = bfr(a.x); r[1] = bfr(a.y); r[2] = bfr(b.x); r[3] = bfr(b.y);
  r[4] = bfr(c.x); r[5] = bfr(c.y); r[6] = bfr(d.x); r[7] = bfr(d.y);
  return r;
}

// ---- fence-free flag sync ----
// set: all threads drain their (coherent) stores, then one relaxed flag store.
DEV void set_flag(unsigned* f, unsigned gen) {
  asm volatile("s_waitcnt vmcnt(0)" ::: "memory");
  __syncthreads();
  if (threadIdx.x == 0)
    __hip_atomic_store(f, gen, __ATOMIC_RELAXED, __HIP_MEMORY_SCOPE_AGENT);
}
// wait: relaxed poll; workgroup fence (waitcnt only, no cache ops) stops reordering.
DEV void wait_flags(unsigned* f, int n, unsigned gen) {
  if (threadIdx.x < (unsigned)n) {
    while (__hip_atomic_load(f + threadIdx.x, __ATOMIC_RELAXED, __HIP_MEMORY_SCOPE_AGENT) < gen)
      ;
  }
  __builtin_amdgcn_fence(__ATOMIC_ACQUIRE, "workgroup");
  __syncthreads();
}

__global__ void zerok(unsigned* p, int n) {
  int i = blockIdx.x * blockDim.x + threadIdx.x;
  if (i < n) p[i] = 0u;
}

// fp32 -> bf16, same layout
__global__ __launch_bounds__(256) void castP(const float* __restrict__ in,
                                             unsigned short* __restrict__ out, int n4) {
  int i = blockIdx.x * blockDim.x + threadIdx.x;
  int stride = gridDim.x * blockDim.x;
  for (; i < n4; i += stride) {
    float4 v = ((const float4*)in)[i];
    ushort4 o;
    o.x = f2bf(v.x); o.y = f2bf(v.y); o.z = f2bf(v.z); o.w = f2bf(v.w);
    ((ushort4*)out)[i] = o;
  }
}

// fp32 [K][N] -> bf16 [N][K] (transpose)
__global__ __launch_bounds__(256) void castT(const float* __restrict__ in,
                                             unsigned short* __restrict__ out, int K, int N) {
  __shared__ unsigned short tile[32][33];
  int tx = threadIdx.x & 31, ty = threadIdx.x >> 5;
  int bx = blockIdx.x, by = blockIdx.y;
  for (int i = ty; i < 32; i += 8)
    tile[i][tx] = f2bf(in[(size_t)(by * 32 + i) * N + bx * 32 + tx]);
  __syncthreads();
  for (int i = ty; i < 32; i += 8)
    out[(size_t)(bx * 32 + i) * K + by * 32 + tx] = tile[tx][i];
}

// C[M][N] (f32 or bf16) = A[M][K]bf16 (optional row gather) @ BT[N][K]bf16 + bias[N]
template <bool GATHER, bool OUTBF>
__global__ __launch_bounds__(256) void gemm_bf16(
    const unsigned short* __restrict__ A, const int* __restrict__ tok,
    const unsigned short* __restrict__ BT, const float* __restrict__ bias,
    void* __restrict__ Cout, int M, int N, int K, int lda, int ldb) {
  __shared__ unsigned short As[128][72];
  __shared__ unsigned short Bs[128][72];
  const int tid = threadIdx.x;
  const int lane = tid & 63, w = tid >> 6;
  const int wr = w >> 1, wc = w & 1;
  const int m0 = blockIdx.y * 128, n0 = blockIdx.x * 128;

  const f32x4 zz = {0.f, 0.f, 0.f, 0.f};
  f32x4 acc[4][4];
#pragma unroll
  for (int i = 0; i < 4; ++i)
#pragma unroll
    for (int j = 0; j < 4; ++j) acc[i][j] = zz;

  for (int kt = 0; kt < K; kt += 64) {
#pragma unroll
    for (int it = 0; it < 4; ++it) {
      int c = it * 256 + tid;
      int row = c >> 3, kb = c & 7;
      size_t arow = GATHER ? (size_t)tok[m0 + row] : (size_t)(m0 + row);
      *(uint4*)&As[row][kb * 8] = *(const uint4*)(A + arow * lda + kt + kb * 8);
      *(uint4*)&Bs[row][kb * 8] = *(const uint4*)(BT + (size_t)(n0 + row) * ldb + kt + kb * 8);
    }
    __syncthreads();
#pragma unroll
    for (int ks = 0; ks < 2; ++ks) {
      int kk = ks * 32 + ((lane >> 4) << 3);
      bf16x8_t af[4], bg[4];
#pragma unroll
      for (int fm = 0; fm < 4; ++fm)
        af[fm] = *(const bf16x8_t*)&As[wr * 64 + fm * 16 + (lane & 15)][kk];
#pragma unroll
      for (int fn = 0; fn < 4; ++fn)
        bg[fn] = *(const bf16x8_t*)&Bs[wc * 64 + fn * 16 + (lane & 15)][kk];
#pragma unroll
      for (int fm = 0; fm < 4; ++fm)
#pragma unroll
        for (int fn = 0; fn < 4; ++fn)
          acc[fm][fn] = MFMA16(af[fm], bg[fn], acc[fm][fn]);
    }
    __syncthreads();
  }
#pragma unroll
  for (int fn = 0; fn < 4; ++fn) {
    int n = n0 + wc * 64 + fn * 16 + (lane & 15);
    float bv = bias[n];
#pragma unroll
    for (int fm = 0; fm < 4; ++fm) {
      int mb = m0 + wr * 64 + fm * 16 + ((lane >> 4) << 2);
#pragma unroll
      for (int j = 0; j < 4; ++j) {
        float v = acc[fm][fn][j] + bv;
        if (OUTBF)
          ((unsigned short*)Cout)[(size_t)(mb + j) * N + n] = f2bf(v);
        else
          ((float*)Cout)[(size_t)(mb + j) * N + n] = v;
      }
    }
  }
}

// Persistent encoder GRU. 32 blocks, block jf owns h cols [jf*16, jf*16+16).
__global__ __launch_bounds__(256) void encoder_gru(
    const float* __restrict__ gxe, const unsigned short* __restrict__ rkT,
    const int* __restrict__ etok, const float* __restrict__ ebr,
    float* __restrict__ hbuf, unsigned short* __restrict__ eob,
    unsigned* __restrict__ flags) {
  __shared__ unsigned short wlds[48][WP];
  __shared__ float partials[4][3][16][16];
  __shared__ float ebrl[48];
  const int tid = threadIdx.x, lane = tid & 63, w = tid >> 6;
  const int jf = blockIdx.x;
  const f32x4 zz = {0.f, 0.f, 0.f, 0.f};

  for (int idx = tid; idx < 3072; idx += 256) {
    int r = idx >> 6, kb = idx & 63;
    int g = r >> 4, jj = r & 15;
    *(uint4*)&wlds[r][kb * 8] =
        *(const uint4*)(rkT + (size_t)(g * 512 + jf * 16 + jj) * 512 + kb * 8);
  }
  if (tid < 48) ebrl[tid] = ebr[(tid >> 4) * 512 + jf * 16 + (tid & 15)];
  { int b = tid >> 4, j = tid & 15; ast1(&hbuf[b * 512 + jf * 16 + j], 0.0f); }
  unsigned gen = 1;
  set_flag(flags + jf, gen);
  wait_flags(flags, NCMP, gen);

  const int rb = tid >> 4, rj = tid & 15, rjg = jf * 16 + rj;
  for (int t = 0; t < TEN; ++t) {
    const float* hcur = hbuf + (t & 1) * 8192;
    float* hnxt = hbuf + ((t & 1) ^ 1) * 8192;
    // prefetch gate inputs (independent of h MFMA; L2-cached, never invalidated)
    const float* gx = gxe + (size_t)(rb * 512 + t) * 1536;
    float gx0 = gx[rjg], gx1 = gx[512 + rjg], gx2 = gx[1024 + rjg];
    int tkv = etok[rb * 512 + t];
    float hold = ald1(&hcur[rb * 512 + rjg]);

    f32x4 a0 = zz, a1 = zz, a2 = zz;
#pragma unroll
    for (int ks = 0; ks < 4; ++ks) {
      int kk = w * 128 + ks * 32 + ((lane >> 4) << 3);
      bf16x8_t af = cvt8a(hcur + (lane & 15) * 512 + kk);
      a0 = MFMA16(af, *(const bf16x8_t*)&wlds[(lane & 15)][kk], a0);
      a1 = MFMA16(af, *(const bf16x8_t*)&wlds[16 + (lane & 15)][kk], a1);
      a2 = MFMA16(af, *(const bf16x8_t*)&wlds[32 + (lane & 15)][kk], a2);
    }
#pragma unroll
    for (int r4 = 0; r4 < 4; ++r4) {
      partials[w][0][(lane >> 4) * 4 + r4][lane & 15] = a0[r4];
      partials[w][1][(lane >> 4) * 4 + r4][lane & 15] = a1[r4];
      partials[w][2][(lane >> 4) * 4 + r4][lane & 15] = a2[r4];
    }
    __syncthreads();
    {
      float g0 = partials[0][0][rb][rj] + partials[1][0][rb][rj] +
                 partials[2][0][rb][rj] + partials[3][0][rb][rj] + ebrl[rj];
      float g1 = partials[0][1][rb][rj] + partials[1][1][rb][rj] +
                 partials[2][1][rb][rj] + partials[3][1][rb][rj] + ebrl[16 + rj];
      float g2 = partials[0][2][rb][rj] + partials[1][2][rb][rj] +
                 partials[2][2][rb][rj] + partials[3][2][rb][rj] + ebrl[32 + rj];
      float z = sigm(gx0 + g0);
      float r = sigm(gx1 + g1);
      float c = tanh1(gx2 + r * g2);
      float hnew = z * hold + (1.0f - z) * c;
      float hv = (tkv != 0) ? hnew : hold;
      ast1(&hnxt[rb * 512 + rjg], hv);
      eob[(size_t)(rb * 512 + t) * 512 + rjg] = f2bf(hv);
    }
    ++gen;
    set_flag(flags + jf, gen);
    wait_flags(flags, NCMP, gen);
  }
}

// Persistent decoder: 160 blocks (32 compute j-slices + 128 attention (b, e-slice)).
__global__ __launch_bounds__(256) void decoder_gru(
    const float* __restrict__ gxd, float* __restrict__ hbuf,
    const unsigned short* __restrict__ keys_bf, const unsigned short* __restrict__ eob,
    const unsigned short* __restrict__ W1T, const unsigned short* __restrict__ drkT,
    const unsigned short* __restrict__ dkT,
    const float* __restrict__ b1, const float* __restrict__ dbr,
    const float* __restrict__ Va, const int* __restrict__ dtok,
    float* __restrict__ qg, float* __restrict__ ctx_part, float* __restrict__ sums_part,
    unsigned short* __restrict__ dob,
    unsigned* __restrict__ flagA, unsigned* __restrict__ flagB, unsigned* __restrict__ flagC) {
  __shared__ __align__(16) char smem[138752];
  const int tid = threadIdx.x, lane = tid & 63, w = tid >> 6;
  const int blk = blockIdx.x;
  const f32x4 zz = {0.f, 0.f, 0.f, 0.f};

  if (blk < NCMP) {
    // ---------------- compute block ----------------
    const int jf = blk;
    unsigned short* w1l = (unsigned short*)smem;   // 16 x WP
    unsigned short* drl = w1l + 16 * WP;           // 48 x WP
    unsigned short* dkl = drl + 48 * WP;           // 48 x WP
    float* partials = (float*)(smem + 2 * 112 * WP);  // [4][4][16][16]
    float* ghl = partials + 4096;                  // [3][16][16]
    float* sinvl = ghl + 768;                      // [16]
    float* cbias = sinvl + 16;                     // [64]: b1 slice + dbr 3x16

    for (int idx = tid; idx < 1024; idx += 256) {
      int r = idx >> 6, kb = idx & 63;
      *(uint4*)&w1l[r * WP + kb * 8] =
          *(const uint4*)(W1T + (size_t)(jf * 16 + r) * 512 + kb * 8);
    }
    for (int idx = tid; idx < 3072; idx += 256) {
      int r = idx >> 6, kb = idx & 63;
      int g = r >> 4, jj = r & 15;
      *(uint4*)&drl[r * WP + kb * 8] =
          *(const uint4*)(drkT + (size_t)(g * 512 + jf * 16 + jj) * 512 + kb * 8);
      *(uint4*)&dkl[r * WP + kb * 8] =
          *(const uint4*)(dkT + (size_t)(g * 512 + jf * 16 + jj) * 768 + kb * 8);
    }
    if (tid < 16) cbias[tid] = b1[jf * 16 + tid];
    if (tid < 48) cbias[16 + tid] = dbr[(tid >> 4) * 512 + jf * 16 + (tid & 15)];
    const int rb = tid >> 4, rj = tid & 15, rjg = jf * 16 + rj;

    for (int t = 0; t < TDN; ++t) {
      wait_flags(flagC, NCMP, (unsigned)t);  // C_{t-1} done everywhere (t=0 trivial)
      const float* hcur = hbuf + (t & 1) * 8192;
      float* hnxt = hbuf + ((t & 1) ^ 1) * 8192;
      float hold = ald1(&hcur[rb * 512 + rjg]);

      // ---- Phase A: q = h@W1+b1 (x2 pre-scale), gh = h@dec_rk+br ----
      f32x4 a0 = zz, a1 = zz, a2 = zz, a3 = zz;
#pragma unroll
      for (int ks = 0; ks < 4; ++ks) {
        int kk = w * 128 + ks * 32 + ((lane >> 4) << 3);
        bf16x8_t af = cvt8a(hcur + (lane & 15) * 512 + kk);
        a0 = MFMA16(af, *(const bf16x8_t*)&w1l[(lane & 15) * WP + kk], a0);
        a1 = MFMA16(af, *(const bf16x8_t*)&drl[(lane & 15) * WP + kk], a1);
        a2 = MFMA16(af, *(const bf16x8_t*)&drl[(16 + (lane & 15)) * WP + kk], a2);
        a3 = MFMA16(af, *(const bf16x8_t*)&drl[(32 + (lane & 15)) * WP + kk], a3);
      }
#pragma unroll
      for (int r4 = 0; r4 < 4; ++r4) {
        int rr = (lane >> 4) * 4 + r4, cc = lane & 15;
        partials[((w * 4 + 0) * 16 + rr) * 16 + cc] = a0[r4];
        partials[((w * 4 + 1) * 16 + rr) * 16 + cc] = a1[r4];
        partials[((w * 4 + 2) * 16 + rr) * 16 + cc] = a2[r4];
        partials[((w * 4 + 3) * 16 + rr) * 16 + cc] = a3[r4];
      }
      __syncthreads();
      {
#define PRD(f) (partials[((0 * 4 + (f)) * 16 + rb) * 16 + rj] + \
                partials[((1 * 4 + (f)) * 16 + rb) * 16 + rj] + \
                partials[((2 * 4 + (f)) * 16 + rb) * 16 + rj] + \
                partials[((3 * 4 + (f)) * 16 + rb) * 16 + rj])
        float qv = PRD(0) + cbias[rj];
        ast1(&qg[rb * 512 + rjg], qv * 2.0f);  // pre-scaled for exp(2x) form of tanh
        ghl[0 * 256 + rb * 16 + rj] = PRD(1) + cbias[16 + rj];
        ghl[1 * 256 + rb * 16 + rj] = PRD(2) + cbias[32 + rj];
        ghl[2 * 256 + rb * 16 + rj] = PRD(3) + cbias[48 + rj];
      }
      set_flag(flagA + jf, (unsigned)(t + 1));
      wait_flags(flagB, NATT, (unsigned)(t + 1));

      // ---- Phase C: gctx = (sum ctx partials / sum p) @ dec_k_ctx; gates ----
      const float* gx = gxd + (size_t)(rb * 128 + t) * 1536;  // L2-hot prefetch
      float gx0 = gx[rjg], gx1 = gx[512 + rjg], gx2 = gx[1024 + rjg];
      int tkv = dtok[rb * 128 + t];
      if (tid < 16) {
        const float* sp = sums_part + tid * 8;
        float s = 0.f;
#pragma unroll
        for (int k = 0; k < 8; ++k) s += ald1(sp + k);
        sinvl[tid] = 1.0f / s;
      }
      __syncthreads();
      float sv = sinvl[lane & 15];
      f32x4 c0 = zz, c1 = zz, c2 = zz;
#pragma unroll
      for (int ks = 0; ks < 4; ++ks) {
        int kk = w * 128 + ks * 32 + ((lane >> 4) << 3);
        float va8[8];
#pragma unroll
        for (int i = 0; i < 8; ++i) va8[i] = 0.f;
#pragma unroll
        for (int q = 0; q < 8; ++q) {
          const float* cp = ctx_part + (size_t)((lane & 15) * 8 + q) * 512 + kk;
          float2 x0 = ald2(cp), x1 = ald2(cp + 2), x2 = ald2(cp + 4), x3 = ald2(cp + 6);
          va8[0] += x0.x; va8[1] += x0.y; va8[2] += x1.x; va8[3] += x1.y;
          va8[4] += x2.x; va8[5] += x2.y; va8[6] += x3.x; va8[7] += x3.y;
        }
        bf16x8_t af;
#pragma unroll
        for (int i = 0; i < 8; ++i) af[i] = bfr(va8[i] * sv);
        c0 = MFMA16(af, *(const bf16x8_t*)&dkl[(lane & 15) * WP + kk], c0);
        c1 = MFMA16(af, *(const bf16x8_t*)&dkl[(16 + (lane & 15)) * WP + kk], c1);
        c2 = MFMA16(af, *(const bf16x8_t*)&dkl[(32 + (lane & 15)) * WP + kk], c2);
      }
#pragma unroll
      for (int r4 = 0; r4 < 4; ++r4) {
        int rr = (lane >> 4) * 4 + r4, cc = lane & 15;
        partials[((w * 4 + 0) * 16 + rr) * 16 + cc] = c0[r4];
        partials[((w * 4 + 1) * 16 + rr) * 16 + cc] = c1[r4];
        partials[((w * 4 + 2) * 16 + rr) * 16 + cc] = c2[r4];
      }
      __syncthreads();
      {
        float gc0 = PRD(0), gc1 = PRD(1), gc2 = PRD(2);
        float z = sigm(gx0 + gc0 + ghl[rb * 16 + rj]);
        float r = sigm(gx1 + gc1 + ghl[256 + rb * 16 + rj]);
        float cc2 = tanh1(gx2 + gc2 + r * ghl[512 + rb * 16 + rj]);
        float hnew = z * hold + (1.0f - z) * cc2;
        float hv = (tkv != 0) ? hnew : hold;
        ast1(&hnxt[rb * 512 + rjg], hv);
        dob[(size_t)(rb * 128 + t) * 512 + rjg] = f2bf((tkv != 0) ? hnew : 0.0f);
#undef PRD
      }
      set_flag(flagC + jf, (unsigned)(t + 1));
    }
  } else {
    // ---------------- attention block ----------------
    const int ab = blk - NCMP, bB = ab >> 3, eq = ab & 7, e0 = eq * 64;
    unsigned short* kl = (unsigned short*)smem;   // 64 x KP (keys*2, bf16)
    unsigned short* el_ = kl + 64 * KP;           // 64 x 512 (enc_out bf16)
    float* qlds = (float*)(el_ + 64 * 512);       // [512]
    float* valds = qlds + 512;                    // [512]
    float* plds = valds + 512;                    // [64]

    for (int idx = tid; idx < 4096; idx += 256) {  // 64 rows x 64 chunks of 8 halfwords
      int el = idx >> 6, kb = idx & 63;
      uint4 v = *(const uint4*)(keys_bf + (size_t)(bB * 512 + e0 + el) * 512 + kb * 8);
      const unsigned short* sp = (const unsigned short*)&v;
      unsigned short tmp[8];
#pragma unroll
      for (int i = 0; i < 8; ++i) tmp[i] = f2bf(bf2f(sp[i]) * 2.0f);  // exact x2
      *(uint2*)&kl[el * KP + kb * 8] = *(uint2*)&tmp[0];
      *(uint2*)&kl[el * KP + kb * 8 + 4] = *(uint2*)&tmp[4];
      uint4 e2 = *(const uint4*)(eob + (size_t)(bB * 512 + e0 + el) * 512 + kb * 8);
      *(uint4*)&el_[el * 512 + kb * 8] = e2;
    }
    valds[tid] = Va[tid];
    valds[tid + 256] = Va[tid + 256];
    __syncthreads();
    const int elr = tid >> 2, hh = (tid & 3) * 128;
    float sva = 0.f;
    for (int i = 0; i < 128; ++i) sva += valds[hh + i];

    for (int t = 0; t < TDN; ++t) {
      wait_flags(flagA, NCMP, (unsigned)(t + 1));
      qlds[tid] = ald1(&qg[bB * 512 + tid]);
      qlds[tid + 256] = ald1(&qg[bB * 512 + tid + 256]);
      __syncthreads();
      // score = Va . tanh(q + keys) ; tanh(x) = 1 - 2/(exp(2x)+1), args pre-scaled x2
      float ra = 0.f, rb2 = 0.f;
#pragma unroll 8
      for (int i = 0; i < 128; i += 2) {
        unsigned kv = *(const unsigned*)&kl[elr * KP + hh + i];
        float s0 = qlds[hh + i] + bf2f((unsigned short)(kv & 0xffffu));
        float s1 = qlds[hh + i + 1] + bf2f((unsigned short)(kv >> 16));
        ra = fmaf(valds[hh + i], __builtin_amdgcn_rcpf(__expf(s0) + 1.0f), ra);
        rb2 = fmaf(valds[hh + i + 1], __builtin_amdgcn_rcpf(__expf(s1) + 1.0f), rb2);
      }
      float part = sva - 2.0f * (ra + rb2);
      part += __shfl_xor(part, 1);
      part += __shfl_xor(part, 2);
      float p = __expf(part);  // no max-subtract: |score| small, softmax invariant
      if ((tid & 3) == 0) plds[elr] = p;
      __syncthreads();
      if (tid < 64) {
        float s = plds[tid];
#pragma unroll
        for (int o = 32; o > 0; o >>= 1) s += __shfl_down(s, o);
        if (tid == 0) ast1(&sums_part[bB * 8 + eq], s);
      }
      {
        int h0 = tid * 2;
        float cc0 = 0.f, cc1 = 0.f;
#pragma unroll 4
        for (int e = 0; e < 64; ++e) {
          float pw = plds[e];
          unsigned v = *(const unsigned*)&el_[e * 512 + h0];
          cc0 = fmaf(pw, bf2f((unsigned short)(v & 0xffffu)), cc0);
          cc1 = fmaf(pw, bf2f((unsigned short)(v >> 16)), cc1);
        }
        ast2(&ctx_part[(size_t)ab * 512 + h0], cc0, cc1);
      }
      set_flag(flagB + ab, (unsigned)(t + 1));
    }
  }
}

extern "C" void kernel_launch(void* const* d_in, const int* in_sizes, int n_in,
                              void* d_out, int out_size, void* d_ws, size_t ws_size,
                              hipStream_t stream) {
  (void)in_sizes; (void)n_in; (void)out_size; (void)ws_size;
  const int* enc_input = (const int*)d_in[0];
  const int* dec_input = (const int*)d_in[1];
  const float* embedding = (const float*)d_in[2];
  const float* enc_k = (const float*)d_in[3];
  const float* enc_rk = (const float*)d_in[4];
  const float* enc_bi = (const float*)d_in[5];
  const float* enc_br = (const float*)d_in[6];
  const float* dec_k = (const float*)d_in[7];
  const float* dec_rk = (const float*)d_in[8];
  const float* dec_bi = (const float*)d_in[9];
  const float* dec_br = (const float*)d_in[10];
  const float* W1 = (const float*)d_in[11];
  const float* b1 = (const float*)d_in[12];
  const float* W2 = (const float*)d_in[13];
  const float* b2 = (const float*)d_in[14];
  const float* Va = (const float*)d_in[15];
  const float* Wd = (const float*)d_in[17];
  const float* bd = (const float*)d_in[18];

  char* ws = (char*)d_ws;
  size_t off = 0;
  auto alloc = [&](size_t bytes) -> char* {
    char* p = ws + off;
    off += (bytes + 255) & ~(size_t)255;
    return p;
  };
  unsigned short* emb_bf  = (unsigned short*)alloc((size_t)VSZ * EDIM * 2);
  unsigned short* enc_kT  = (unsigned short*)alloc((size_t)G3H * EDIM * 2);
  unsigned short* enc_rkT = (unsigned short*)alloc((size_t)G3H * HDIM * 2);
  unsigned short* W1T     = (unsigned short*)alloc((size_t)HDIM * HDIM * 2);
  unsigned short* W2T     = (unsigned short*)alloc((size_t)HDIM * HDIM * 2);
  unsigned short* dec_kT  = (unsigned short*)alloc((size_t)G3H * (HDIM + EDIM) * 2);
  unsigned short* dec_rkT = (unsigned short*)alloc((size_t)G3H * HDIM * 2);
  unsigned short* WdT     = (unsigned short*)alloc((size_t)VSZ * HDIM * 2);
  unsigned short* eob     = (unsigned short*)alloc((size_t)BSZ * TEN * HDIM * 2);
  unsigned short* keys_bf = (unsigned short*)alloc((size_t)BSZ * TEN * HDIM * 2);
  unsigned short* dob     = (unsigned short*)alloc((size_t)BSZ * TDN * HDIM * 2);
  float* hbuf      = (float*)alloc((size_t)2 * BSZ * HDIM * 4);
  float* qg        = (float*)alloc((size_t)BSZ * HDIM * 4);
  float* ctx_part  = (float*)alloc((size_t)NATT * HDIM * 4);
  float* sums_part = (float*)alloc((size_t)BSZ * 8 * 4);
  unsigned* bars   = (unsigned*)alloc(1024);

  // d_out doubles as scratch for the precomputed input-gate activations (dead
  // before the final logits GEMM overwrites the whole output).
  float* outp = (float*)d_out;
  float* gxe = outp;                               // [8192][1536]
  float* gxd = outp + (size_t)BSZ * TEN * G3H;     // [2048][1536]

  castP<<<2048, 256, 0, stream>>>(embedding, emb_bf, VSZ * EDIM / 4);
  castT<<<dim3(G3H / 32, EDIM / 32), 256, 0, stream>>>(enc_k, enc_kT, EDIM, G3H);
  castT<<<dim3(G3H / 32, HDIM / 32), 256, 0, stream>>>(enc_rk, enc_rkT, HDIM, G3H);
  castT<<<dim3(HDIM / 32, HDIM / 32), 256, 0, stream>>>(W1, W1T, HDIM, HDIM);
  castT<<<dim3(HDIM / 32, HDIM / 32), 256, 0, stream>>>(W2, W2T, HDIM, HDIM);
  castT<<<dim3(G3H / 32, (HDIM + EDIM) / 32), 256, 0, stream>>>(dec_k, dec_kT, HDIM + EDIM, G3H);
  castT<<<dim3(G3H / 32, HDIM / 32), 256, 0, stream>>>(dec_rk, dec_rkT, HDIM, G3H);
  castT<<<dim3(VSZ / 32, HDIM / 32), 256, 0, stream>>>(Wd, WdT, HDIM, VSZ);
  zerok<<<1, 256, 0, stream>>>(bars, 256);

  // gxe = emb[enc_input] @ enc_k + enc_bi
  gemm_bf16<true, false><<<dim3(G3H / 128, BSZ * TEN / 128), 256, 0, stream>>>(
      emb_bf, enc_input, enc_kT, enc_bi, gxe, BSZ * TEN, G3H, EDIM, EDIM, EDIM);
  // encoder recurrence
  encoder_gru<<<NCMP, 256, 0, stream>>>(gxe, enc_rkT, enc_input, enc_br, hbuf, eob, bars);
  // keys = enc_out @ W2 + b2 (bf16 out)
  gemm_bf16<false, true><<<dim3(HDIM / 128, BSZ * TEN / 128), 256, 0, stream>>>(
      eob, nullptr, W2T, b2, keys_bf, BSZ * TEN, HDIM, HDIM, HDIM, HDIM);
  // gxd = emb[dec_input] @ dec_k[H:] + dec_bi
  gemm_bf16<true, false><<<dim3(G3H / 128, BSZ * TDN / 128), 256, 0, stream>>>(
      emb_bf, dec_input, dec_kT + HDIM, dec_bi, gxd, BSZ * TDN, G3H, EDIM, EDIM, HDIM + EDIM);
  // decoder recurrence + attention (32 compute + 128 attention blocks)
  decoder_gru<<<NCMP + NATT, 256, 0, stream>>>(
      gxd, hbuf, keys_bf, eob, W1T, dec_rkT, dec_kT, b1, dec_br, Va, dec_input,
      qg, ctx_part, sums_part, dob, bars + 32, bars + 64, bars + 192);
  // logits = dec_out @ Wd + bd
  gemm_bf16<false, false><<<dim3(VSZ / 128, BSZ * TDN / 128), 256, 0, stream>>>(
      dob, nullptr, WdT, bd, outp, BSZ * TDN, VSZ, HDIM, HDIM, HDIM);
}